// Round 9
// baseline (143.590 us; speedup 1.0000x reference)
//
#include <hip/hip_runtime.h>

// SSIM fused, v18: v17 + in-kernel sequential L3 warm.
// v17 post-mortem: 48KB block changed nothing (44.5us, occ ~25%). Re-derived
// across ALL rounds: time == hbm_bytes / achieved_BW for every version
// (v9 112MB@2.1=53, v10 238MB@3.1=77, v12 343MB@3.0=116, v13 101MB@2.2=46,
// v16/17 98MB@2.2=44). The kernel is HBM-bound at ~2.2TB/s PATTERN
// efficiency: each block first-touches ~288B per 2KB image row; 8 blocks
// share each DRAM row at dispersed times -> ~7 activations/row -> ~30% DRAM
// efficiency (2.2/6.3). Spill versions' streaming scratch hit 3.0TB/s ->
// efficiency is pattern-dependent. FETCH ~96MB == unique input (L3 would
// hold it, but the harness's 2x268MB fills flush L3 each iteration).
// v18: make the HBM first-touch sequential. Each of 768 blocks streams one
// CONTIGUOUS 128KB region (768x128KB == the full 96MB input) via 32
// global_load_lds into a dummy H-ring slot before its tile work:
//   - no registers, no DCE risk (LDS write is a side effect);
//   - vmcnt-counted, drained by the pipeline's first vwait(4) (in-order
//     retire => granule-0 data still provably complete);
//   - dummy dest = H ring, which is only written later (no clobber);
//   - tile reads then hit L3/L2 instead of 30%-efficient DRAM.
// Compute structure/schedule/math byte-identical to harness-verified v17.

#define IMG 512
#define NPIX (16LL * 3 * 512 * 512)
#define GX 8                  /* 32 col-tiles / 4 waves per block */
#define GY 2                  /* 512 rows / 256 rows per wave */
#define NG 16                 /* output granules (16 rows) per wave */
#define NBLK (GX * GY * 48)   /* 768 blocks */
#define NPART NBLK            /* one float per block: 3 KB */

typedef short v8s __attribute__((ext_vector_type(8)));   // 8 x bf16 (4 VGPRs)
typedef float v4f __attribute__((ext_vector_type(4)));   // MFMA accumulator
typedef __bf16 bf2 __attribute__((ext_vector_type(2)));
typedef float f2  __attribute__((ext_vector_type(2)));

static __device__ __forceinline__ int cvtpk2(f2 v) {     // v_cvt_pk_bf16_f32
    bf2 r = __builtin_convertvector(v, bf2);
    return __builtin_bit_cast(int, r);
}
static __device__ __forceinline__ unsigned f2bf(float f) {
    unsigned u = __float_as_uint(f);
    return (u + 0x7FFFu + ((u >> 16) & 1u)) >> 16;
}

// Async 16B/lane global->LDS. Dest is wave-uniform base; lane i lands at
// base + i*16. Source address is per-lane.
static __device__ __forceinline__ void gload16(const void* g, void* lds) {
    __builtin_amdgcn_global_load_lds(
        (const __attribute__((address_space(1))) void*)g,
        (__attribute__((address_space(3))) void*)lds, 16, 0, 0);
}

template <int N>
static __device__ __forceinline__ void vwait() {
    if constexpr (N == 4) asm volatile("s_waitcnt vmcnt(4)" ::: "memory");
    else                  asm volatile("s_waitcnt vmcnt(0)" ::: "memory");
}
static __device__ __forceinline__ void lwait0() {
    asm volatile("s_waitcnt lgkmcnt(0)" ::: "memory");
    __builtin_amdgcn_sched_barrier(0);   // rule #18: fence reg-only reordering
}

// h-pass for one 16-row granule: pack 4 planes to bf16, 4 MFMA, write H ring.
// H layout per wave: plane p at hw + p*1024; col lm, short s (0..31) at byte
// ((lm*64 + (s/8)*16) ^ ((lm&7)<<4)) + (s%8)*2. Write: s = slot*16+quad*4.
static __device__ __forceinline__ void h_rt(
    const float4 (&L)[4], v8s band, char* hw, int lm, int quad, int slot)
{
    const v4f zacc = {0.f, 0.f, 0.f, 0.f};
    const float4 a0 = L[0], a1 = L[1], b0 = L[2], b1 = L[3];
    f2 a0l; a0l.x = a0.x; a0l.y = a0.y;   f2 a0h; a0h.x = a0.z; a0h.y = a0.w;
    f2 a1l; a1l.x = a1.x; a1l.y = a1.y;   f2 a1h; a1h.x = a1.z; a1h.y = a1.w;
    f2 b0l; b0l.x = b0.x; b0l.y = b0.y;   f2 b0h; b0h.x = b0.z; b0h.y = b0.w;
    f2 b1l; b1l.x = b1.x; b1l.y = b1.y;   f2 b1h; b1h.x = b1.z; b1h.y = b1.w;

    v8s A[4]; int4 w;
    w.x = cvtpk2(a0l); w.y = cvtpk2(a0h); w.z = cvtpk2(a1l); w.w = cvtpk2(a1h);
    A[0] = __builtin_bit_cast(v8s, w);
    w.x = cvtpk2(b0l); w.y = cvtpk2(b0h); w.z = cvtpk2(b1l); w.w = cvtpk2(b1h);
    A[1] = __builtin_bit_cast(v8s, w);
    w.x = cvtpk2(__builtin_elementwise_fma(a0l, a0l, b0l * b0l));
    w.y = cvtpk2(__builtin_elementwise_fma(a0h, a0h, b0h * b0h));
    w.z = cvtpk2(__builtin_elementwise_fma(a1l, a1l, b1l * b1l));
    w.w = cvtpk2(__builtin_elementwise_fma(a1h, a1h, b1h * b1h));
    A[2] = __builtin_bit_cast(v8s, w);
    w.x = cvtpk2(a0l * b0l); w.y = cvtpk2(a0h * b0h);
    w.z = cvtpk2(a1l * b1l); w.w = cvtpk2(a1h * b1h);
    A[3] = __builtin_bit_cast(v8s, w);

    // write byte: chunk = slot*2 + (quad>>1), within-chunk = (quad&1)*8
    const int wsel = ((lm * 64 + (slot * 2 + (quad >> 1)) * 16) ^ ((lm & 7) << 4))
                     + (quad & 1) * 8;
    #pragma unroll
    for (int p = 0; p < 4; ++p) {
        const v4f acc = __builtin_amdgcn_mfma_f32_16x16x32_bf16(A[p], band, zacc, 0, 0, 0);
        // D C-layout: col = lm, rows quad*4 + reg -> ring slot, col-major write.
        int2 w2;
        f2 lo; lo.x = acc[0]; lo.y = acc[1];
        f2 hi; hi.x = acc[2]; hi.y = acc[3];
        w2.x = cvtpk2(lo); w2.y = cvtpk2(hi);
        *(int2*)(hw + p * 1024 + wsel) = w2;
    }
}

// v-pass for output granule o (ring window = granules o, o+1) + SSIM accumulate.
static __device__ __forceinline__ void v_t2(
    v8s band, char* hw, int lm, int quad, int o, f2& vsum)
{
    const v4f zacc = {0.f, 0.f, 0.f, 0.f};
    // shorts bs..bs+7, bs=(quad*8+o*16)&31 -> chunk (quad+2o)&3, swizzled.
    const int rsel = (lm * 64 + (((quad + 2 * o) & 3) * 16)) ^ ((lm & 7) << 4);
    v4f acc[4];
    #pragma unroll
    for (int p = 0; p < 4; ++p) {
        const v8s hf = *(const v8s*)(hw + p * 1024 + rsel);
        acc[p] = __builtin_amdgcn_mfma_f32_16x16x32_bf16(band, hf, zacc, 0, 0, 0);
    }
    const f2 C1v = {1e-4f, 1e-4f};        // 0.01^2
    const f2 C2v = {9e-4f, 9e-4f};        // 0.03^2
    const f2 two = {2.f, 2.f};
    #pragma unroll
    for (int h = 0; h < 2; ++h) {
        f2 m1; m1.x = acc[0][2 * h]; m1.y = acc[0][2 * h + 1];
        f2 m2; m2.x = acc[1][2 * h]; m2.y = acc[1][2 * h + 1];
        f2 es; es.x = acc[2][2 * h]; es.y = acc[2][2 * h + 1];
        f2 ex; ex.x = acc[3][2 * h]; ex.y = acc[3][2 * h + 1];
        const f2 m1s = m1 * m1, m2s = m2 * m2, m12 = m1 * m2;
        const f2 sig = es - m1s - m2s;                  // sig1_sq + sig2_sq
        const f2 s12 = ex - m12;
        const f2 num = __builtin_elementwise_fma(two, m12, C1v) *
                       __builtin_elementwise_fma(two, s12, C2v);
        const f2 den = (m1s + m2s + C1v) * (sig + C2v);
        f2 r; r.x = __builtin_amdgcn_rcpf(den.x); r.y = __builtin_amdgcn_rcpf(den.y);
        vsum = __builtin_elementwise_fma(num, r, vsum);
    }
}

__global__ __launch_bounds__(256, 3) void ssim_kernel(
    const float* __restrict__ img1,
    const float* __restrict__ img2,
    const float* __restrict__ win,
    float* __restrict__ partial)
{
    // H ring: [wave][4 planes x 1KB] = 16384 B (zero-pad, XOR-swizzled).
    __shared__ __align__(16) char hraw[4][4096];
    // Raw ring: [wave][slot][4096B] = 32768 B. Block total 49152 B.
    __shared__ __align__(16) char raw[4][2][4096];

    const int tid  = threadIdx.x;
    const int lane = tid & 63;
    const int wave = tid >> 6;
    const int lm   = lane & 15;
    const int quad = lane >> 4;

    const int bx = blockIdx.x, by = blockIdx.y, z = blockIdx.z;
    const int rowbase = by * (NG * 16);

    const size_t zoff = (size_t)z * IMG * IMG;
    const char* p1 = (const char*)(img1 + zoff);
    const char* p2 = (const char*)(img2 + zoff);

    // ---- L3 warm: this block streams one CONTIGUOUS 128KB region ----
    // 768 blocks x 128KB == the entire 96MB input. Sequential multi-stream
    // reads run at streaming DRAM efficiency; the tile reads below then hit
    // L3/L2. Dest is a dummy H-ring slot (H is written only after vwait+h_rt,
    // and vmcnt retires in order, so these all land first). All issued before
    // issue_g(0): the first vwait(4) naturally drains them.
    {
        const int bid = (z * GY + by) * GX + bx;
        const char* src = (bid < 384 ? (const char*)img1 : (const char*)img2)
                        + (size_t)(bid < 384 ? bid : bid - 384) * 131072
                        + (size_t)tid * 16;
        char* dst = &hraw[wave][0];
        #pragma unroll
        for (int i = 0; i < 32; ++i)
            gload16(src + (size_t)i * 4096, dst + ((i & 3) << 10));
        __builtin_amdgcn_sched_barrier(0);
    }

    // Band fragment via shuffle: value g[k-i-3], i = lane&15, k = quad*8+j.
    // (VALU-only; overlaps the warm loads' flight time.)
    float gl = 0.f;
    if (lane < 11) gl = win[55 + lane] * rsqrtf(win[60]);
    v8s band;
    #pragma unroll
    for (int j = 0; j < 8; ++j) {
        const int t  = quad * 8 + j - lm - 3;
        const int tc = ((unsigned)t > 10u) ? 11 : t;   // lane 11 holds 0
        band[j] = (short)f2bf(__shfl(gl, tc));
    }

    // One 16-col tile per wave, 256-row strip.
    const int gct = bx * 4 + wave;
    const bool colOK = (gct > 0) & (gct < 31);
    const int gcol = gct * 16 - 8 + quad * 8;          // reader's float col
    const bool cbA  = (unsigned)gcol >= (unsigned)IMG;
    const bool cbB  = (unsigned)(gcol + 4) >= (unsigned)IMG;
    const bool topE = (by == 0), botE = (by == GY - 1);
    char* hw = hraw[wave];

    // ---- coalesced staging maps (per-lane constants) ----
    // Loader lane L of gload g: source row = 8g + (L>>3), logical col-piece
    // = (L&7) ^ ((L>>3)&7)  (source-side swizzle; LDS dest stays linear).
    const int rowoff = lane >> 3;                       // 0..7
    int cb = gct * 64 - 32 + (((lane & 7) ^ (rowoff & 7)) << 4);
    cb = cb < 0 ? 0 : (cb > 2032 ? 2032 : cb);          // clamp into row
    const int colbyte = cb;
    // Reader lane (lm,quad): pieces 2q,2q+1 of row lm, swizzled readback.
    const int off0 = lm * 128 + (((2 * quad)     ^ (lm & 7)) << 4);
    const int off1 = lm * 128 + (((2 * quad + 1) ^ (lm & 7)) << 4);

    // Issue granule k's 4 async loads into raw slot k&1. Each instruction
    // reads 8 rows x 128B CONTIGUOUS (full TA merging).
    auto issue_g = [&](int k) {
        const int rb = rowbase + k * 16 - 8;
        int r0 = rb + rowoff;      r0 = r0 < 0 ? 0 : (r0 > IMG - 1 ? IMG - 1 : r0);
        int r1 = rb + 8 + rowoff;  r1 = r1 < 0 ? 0 : (r1 > IMG - 1 ? IMG - 1 : r1);
        char* s = &raw[wave][k & 1][0];
        gload16(p1 + (size_t)r0 * 2048 + colbyte, s);
        gload16(p1 + (size_t)r1 * 2048 + colbyte, s + 1024);
        gload16(p2 + (size_t)r0 * 2048 + colbyte, s + 2048);
        gload16(p2 + (size_t)r1 * 2048 + colbyte, s + 3072);
    };
    // Read granule k from LDS into regs + zero-fix edges. lwait0 pins the
    // data into VGPRs before the caller may re-issue this slot (WAR).
    auto read_g = [&](int k, float4 (&L)[4], bool rowsE) {
        const char* s = &raw[wave][k & 1][0];
        L[0] = *(const float4*)(s + off0);
        L[1] = *(const float4*)(s + off1);
        L[2] = *(const float4*)(s + off0 + 2048);
        L[3] = *(const float4*)(s + off1 + 2048);
        lwait0();
        if (!colOK || rowsE) {                     // wave-uniform branch
            const int gr = rowbase + k * 16 - 8 + lm;
            const bool rbad = (unsigned)gr >= (unsigned)IMG;
            float4 zz; zz.x = zz.y = zz.z = zz.w = 0.f;
            if (rbad | cbA) { L[0] = zz; L[2] = zz; }
            if (rbad | cbB) { L[1] = zz; L[3] = zz; }
        }
    };

    f2 vsum = {0.f, 0.f};
    float4 L[4];

    // Pipeline: distance-2 issue->consume, vmcnt(4) steady (granule k lands,
    // k+1 stays in flight), tail 4 then 0.
    issue_g(0); issue_g(1);

    // k = 0 (possible top edge)
    vwait<4>(); read_g(0, L, topE);
    issue_g(2);
    h_rt(L, band, hw, lm, quad, 0);

    #pragma unroll 2
    for (int k = 1; k <= NG - 2; ++k) {            // k = 1..14
        vwait<4>(); read_g(k, L, false);
        issue_g(k + 2);
        h_rt(L, band, hw, lm, quad, k & 1);
        v_t2(band, hw, lm, quad, k - 1, vsum);
    }

    // k = NG-1 (no more issues)
    vwait<4>(); read_g(NG - 1, L, false);
    h_rt(L, band, hw, lm, quad, (NG - 1) & 1);
    v_t2(band, hw, lm, quad, NG - 2, vsum);

    // k = NG (possible bottom edge)
    vwait<0>(); read_g(NG, L, botE);
    h_rt(L, band, hw, lm, quad, NG & 1);
    v_t2(band, hw, lm, quad, NG - 1, vsum);

    // ---- wave reduction, per-BLOCK partial parked in the dead raw ring ----
    float vs = vsum.x + vsum.y;
    #pragma unroll
    for (int off = 32; off > 0; off >>= 1)
        vs += __shfl_down(vs, off, 64);
    if (lane == 0) *(float*)&raw[wave][0][0] = vs;       // raw is dead here
    __syncthreads();
    if (tid == 0) {
        float t = 0.f;
        #pragma unroll
        for (int w = 0; w < 4; ++w) t += *(const float*)&raw[w][0][0];
        partial[(z * GY + by) * GX + bx] = t;
    }
}

__global__ __launch_bounds__(512) void finalize_kernel(
    const float* __restrict__ partial, float* __restrict__ out)
{
    __shared__ float red[8];
    float s = 0.f;
    if (threadIdx.x < NPART / 4) {                      // 192 float4s
        const float4 t = ((const float4*)partial)[threadIdx.x];
        s = (t.x + t.y) + (t.z + t.w);
    }
    #pragma unroll
    for (int off = 32; off > 0; off >>= 1)
        s += __shfl_down(s, off, 64);
    if ((threadIdx.x & 63) == 0) red[threadIdx.x >> 6] = s;
    __syncthreads();
    if (threadIdx.x == 0) {
        float t = 0.f;
        #pragma unroll
        for (int i = 0; i < 8; ++i) t += red[i];
        out[0] = 1.0f - t / (float)NPIX;
    }
}

extern "C" void kernel_launch(void* const* d_in, const int* in_sizes, int n_in,
                              void* d_out, int out_size, void* d_ws, size_t ws_size,
                              hipStream_t stream) {
    const float* img1 = (const float*)d_in[0];
    const float* img2 = (const float*)d_in[1];
    const float* win  = (const float*)d_in[2];
    float* partialb = (float*)d_ws;  // NPART floats = 3 KB; fully rewritten each call

    dim3 grid(GX, GY, 48);
    ssim_kernel<<<grid, dim3(256), 0, stream>>>(img1, img2, win, partialb);
    finalize_kernel<<<1, dim3(512), 0, stream>>>(partialb, (float*)d_out);
}

// Round 10
// 130.120 us; speedup vs baseline: 1.1035x; 1.1035x over previous
//
#include <hip/hip_runtime.h>

// SSIM fused, v19: block-cooperative SEQUENTIAL staging (single pass).
// v18 post-mortem: L3 pre-warm doubled traffic (FETCH 96->145MB, 55us) --
// warm/consume timing mismatch. But it measured the key fact: sequential
// streams run ~4.5TB/s vs 2.2 for the tile pattern; and time==bytes/BW held
// for the 10th straight version. Fix must raise run length IN the one pass.
// v19: 1024-thread blocks (16 waves), 256-col x 128-row band:
//   - staging per 16-row granule = 36 global_load_lds, each a fully
//     CONTIGUOUS 1KB of the image (runs 352B -> 1088B/row, rows consecutive).
//   - LDS slab row stride 1104B (276 dw == 20 mod 32 -> readback banks
//     rotate, perfectly balanced 8 dw/bank). Lane source mapping precomputed
//     once via magic-div row=(off*60788)>>26 (exact for off<17664, verified).
//   - 2 raw s_barriers per granule (NOT __syncthreads -- that would emit
//     vmcnt(0) and drain the prefetch): bar1 after own counted vwait
//     (3 for waves 0-3, 2 for 4-15, readfirstlane-uniform), bar2 closes the
//     WAR on the 2-slot ring before re-issue. sched_barrier(0) after each.
//   - compute core (h_rt/v_t2/H-ring 4KB/wave/band/zero-fix) byte-identical
//     to harness-verified v17; only staging->readback mapping changed.
//   - LDS 73728 raw + 65536 H = 136KB -> 1 block/CU (4 waves/SIMD);
//     grid 2x4x48 = 384 blocks.

#define IMG 512
#define NPIX (16LL * 3 * 512 * 512)
#define GXC 2                  /* col-bands of 256 cols */
#define GYB 4                  /* row-bands of 128 rows */
#define NG 8                   /* output granules (16 rows) per block */
#define NBLK (GXC * GYB * 48)  /* 384 blocks */
#define NPART NBLK             /* one float per block: 1.5 KB */
#define SLAB 18432             /* per-img LDS slab (useful 16x1104=17664) */
#define RSTR 1104              /* staged row stride: 276 dw == 20 mod 32 */

typedef short v8s __attribute__((ext_vector_type(8)));   // 8 x bf16 (4 VGPRs)
typedef float v4f __attribute__((ext_vector_type(4)));   // MFMA accumulator
typedef __bf16 bf2 __attribute__((ext_vector_type(2)));
typedef float f2  __attribute__((ext_vector_type(2)));

static __device__ __forceinline__ int cvtpk2(f2 v) {     // v_cvt_pk_bf16_f32
    bf2 r = __builtin_convertvector(v, bf2);
    return __builtin_bit_cast(int, r);
}
static __device__ __forceinline__ unsigned f2bf(float f) {
    unsigned u = __float_as_uint(f);
    return (u + 0x7FFFu + ((u >> 16) & 1u)) >> 16;
}

// Async 16B/lane global->LDS. Dest wave-uniform base; lane i at base + i*16.
static __device__ __forceinline__ void gload16(const void* g, void* lds) {
    __builtin_amdgcn_global_load_lds(
        (const __attribute__((address_space(1))) void*)g,
        (__attribute__((address_space(3))) void*)lds, 16, 0, 0);
}

template <int N>
static __device__ __forceinline__ void vwait() {
    if constexpr (N == 3)      asm volatile("s_waitcnt vmcnt(3)" ::: "memory");
    else if constexpr (N == 2) asm volatile("s_waitcnt vmcnt(2)" ::: "memory");
    else                       asm volatile("s_waitcnt vmcnt(0)" ::: "memory");
}
static __device__ __forceinline__ void lwait0() {
    asm volatile("s_waitcnt lgkmcnt(0)" ::: "memory");
    __builtin_amdgcn_sched_barrier(0);   // rule #18
}
static __device__ __forceinline__ void blockbar() {
    __builtin_amdgcn_s_barrier();        // raw: no vmcnt(0) drain
    __builtin_amdgcn_sched_barrier(0);   // pin ds ops below the barrier
}

// h-pass for one 16-row granule (v17 verbatim): pack 4 planes, 4 MFMA, H ring.
static __device__ __forceinline__ void h_rt(
    const float4 (&L)[4], v8s band, char* hw, int lm, int quad, int slot)
{
    const v4f zacc = {0.f, 0.f, 0.f, 0.f};
    const float4 a0 = L[0], a1 = L[1], b0 = L[2], b1 = L[3];
    f2 a0l; a0l.x = a0.x; a0l.y = a0.y;   f2 a0h; a0h.x = a0.z; a0h.y = a0.w;
    f2 a1l; a1l.x = a1.x; a1l.y = a1.y;   f2 a1h; a1h.x = a1.z; a1h.y = a1.w;
    f2 b0l; b0l.x = b0.x; b0l.y = b0.y;   f2 b0h; b0h.x = b0.z; b0h.y = b0.w;
    f2 b1l; b1l.x = b1.x; b1l.y = b1.y;   f2 b1h; b1h.x = b1.z; b1h.y = b1.w;

    v8s A[4]; int4 w;
    w.x = cvtpk2(a0l); w.y = cvtpk2(a0h); w.z = cvtpk2(a1l); w.w = cvtpk2(a1h);
    A[0] = __builtin_bit_cast(v8s, w);
    w.x = cvtpk2(b0l); w.y = cvtpk2(b0h); w.z = cvtpk2(b1l); w.w = cvtpk2(b1h);
    A[1] = __builtin_bit_cast(v8s, w);
    w.x = cvtpk2(__builtin_elementwise_fma(a0l, a0l, b0l * b0l));
    w.y = cvtpk2(__builtin_elementwise_fma(a0h, a0h, b0h * b0h));
    w.z = cvtpk2(__builtin_elementwise_fma(a1l, a1l, b1l * b1l));
    w.w = cvtpk2(__builtin_elementwise_fma(a1h, a1h, b1h * b1h));
    A[2] = __builtin_bit_cast(v8s, w);
    w.x = cvtpk2(a0l * b0l); w.y = cvtpk2(a0h * b0h);
    w.z = cvtpk2(a1l * b1l); w.w = cvtpk2(a1h * b1h);
    A[3] = __builtin_bit_cast(v8s, w);

    const int wsel = ((lm * 64 + (slot * 2 + (quad >> 1)) * 16) ^ ((lm & 7) << 4))
                     + (quad & 1) * 8;
    #pragma unroll
    for (int p = 0; p < 4; ++p) {
        const v4f acc = __builtin_amdgcn_mfma_f32_16x16x32_bf16(A[p], band, zacc, 0, 0, 0);
        int2 w2;
        f2 lo; lo.x = acc[0]; lo.y = acc[1];
        f2 hi; hi.x = acc[2]; hi.y = acc[3];
        w2.x = cvtpk2(lo); w2.y = cvtpk2(hi);
        *(int2*)(hw + p * 1024 + wsel) = w2;
    }
}

// v-pass for output granule o + SSIM accumulate (v17 verbatim).
static __device__ __forceinline__ void v_t2(
    v8s band, char* hw, int lm, int quad, int o, f2& vsum)
{
    const v4f zacc = {0.f, 0.f, 0.f, 0.f};
    const int rsel = (lm * 64 + (((quad + 2 * o) & 3) * 16)) ^ ((lm & 7) << 4);
    v4f acc[4];
    #pragma unroll
    for (int p = 0; p < 4; ++p) {
        const v8s hf = *(const v8s*)(hw + p * 1024 + rsel);
        acc[p] = __builtin_amdgcn_mfma_f32_16x16x32_bf16(band, hf, zacc, 0, 0, 0);
    }
    const f2 C1v = {1e-4f, 1e-4f};
    const f2 C2v = {9e-4f, 9e-4f};
    const f2 two = {2.f, 2.f};
    #pragma unroll
    for (int h = 0; h < 2; ++h) {
        f2 m1; m1.x = acc[0][2 * h]; m1.y = acc[0][2 * h + 1];
        f2 m2; m2.x = acc[1][2 * h]; m2.y = acc[1][2 * h + 1];
        f2 es; es.x = acc[2][2 * h]; es.y = acc[2][2 * h + 1];
        f2 ex; ex.x = acc[3][2 * h]; ex.y = acc[3][2 * h + 1];
        const f2 m1s = m1 * m1, m2s = m2 * m2, m12 = m1 * m2;
        const f2 sig = es - m1s - m2s;
        const f2 s12 = ex - m12;
        const f2 num = __builtin_elementwise_fma(two, m12, C1v) *
                       __builtin_elementwise_fma(two, s12, C2v);
        const f2 den = (m1s + m2s + C1v) * (sig + C2v);
        f2 r; r.x = __builtin_amdgcn_rcpf(den.x); r.y = __builtin_amdgcn_rcpf(den.y);
        vsum = __builtin_elementwise_fma(num, r, vsum);
    }
}

__global__ __launch_bounds__(1024) void ssim_kernel(
    const float* __restrict__ img1,
    const float* __restrict__ img2,
    const float* __restrict__ win,
    float* __restrict__ partial)
{
    // Raw ring: 2 slots x [img0 SLAB][img1 SLAB] = 73728 B.
    __shared__ __align__(16) char raw[2][2 * SLAB];
    // H ring: per-wave 4KB (4 planes x 1KB, XOR-swizzled) = 65536 B.
    __shared__ __align__(16) char hraw[16][4096];

    const int tid  = threadIdx.x;
    const int lane = tid & 63;
    const int wave = tid >> 6;             // 0..15
    const int lm   = lane & 15;
    const int quad = lane >> 4;
    const int wuni = __builtin_amdgcn_readfirstlane(wave);   // provably uniform

    const int bxc = blockIdx.x;            // col-band 0..1
    const int byb = blockIdx.y;            // row-band 0..3
    const int z   = blockIdx.z;            // 0..47
    const int rowbase = byb * (NG * 16);

    // Band fragment via shuffle (v17 verbatim).
    float gl = 0.f;
    if (lane < 11) gl = win[55 + lane] * rsqrtf(win[60]);
    v8s band;
    #pragma unroll
    for (int j = 0; j < 8; ++j) {
        const int t  = quad * 8 + j - lm - 3;
        const int tc = ((unsigned)t > 10u) ? 11 : t;
        band[j] = (short)f2bf(__shfl(gl, tc));
    }

    const size_t zoff = (size_t)z * IMG * IMG;
    const char* p1 = (const char*)(img1 + zoff);
    const char* p2 = (const char*)(img2 + zoff);

    // Per-wave output columns + edge flags.
    const int gcol = bxc * 256 + wave * 16 - 8 + quad * 8;
    const bool cbA = (unsigned)gcol >= (unsigned)IMG;
    const bool cbB = (unsigned)(gcol + 4) >= (unsigned)IMG;
    const bool colOK = !((bxc == 0) & (wave == 0)) & !((bxc == 1) & (wave == 15));
    const bool topE = (byb == 0), botE = (byb == GYB - 1);
    char* hw = hraw[wave];

    // ---- staging slot precompute (per-lane constants, 3 named slots) ----
    // Instr j covers slot bytes [j*1024, +1024), lane l at j*1024 + l*16.
    // Slot byte o: img = o>=SLAB; off = o - img*SLAB; row = off/1104 (magic),
    // colb = off%1104 (colb>=1088 = pad -> clamp). Source: img base +
    // clamp(bxc*1024 - 32 + colb) + row*2048 (row added per granule).
    const bool has3 = (wuni < 4);
    const char* base0; const char* base1; const char* base2;
    int ro_0, ro_1, ro_2, dst0, dst1, dst2;
    {
        int js0 = 2 * wave, js1 = 2 * wave + 1, js2 = 32 + wave;
        #define PREP(J, BASE, ROFF, DST)                                     \
        {                                                                    \
            const int offT = (J) * 1024 + lane * 16;                         \
            const int im   = offT >= SLAB;                                   \
            int off = offT - im * SLAB;                                      \
            if (off > 17663) off = 17663;                                    \
            int row = (int)(((unsigned)off * 60788u) >> 26);                 \
            int colb = off - row * RSTR;                                     \
            if (colb > 1072) colb = 1072;      /* row pad -> safe col */     \
            int g = bxc * 1024 - 32 + colb;                                  \
            g = g < 0 ? 0 : (g > 2032 ? 2032 : g);                           \
            BASE = (im ? p2 : p1) + g;                                       \
            ROFF = row;                                                      \
            DST  = (J) * 1024;                                               \
        }
        PREP(js0, base0, ro_0, dst0)
        PREP(js1, base1, ro_1, dst1)
        PREP(js2, base2, ro_2, dst2)
        #undef PREP
    }

    // Issue granule k: 2 (or 3) contiguous-1KB gloads into raw slot k&1.
    auto issue_g = [&](int k) {
        const int r0 = rowbase + k * 16 - 8;
        char* slot = &raw[k & 1][0];
        int r;
        r = r0 + ro_0; r = r < 0 ? 0 : (r > IMG - 1 ? IMG - 1 : r);
        gload16(base0 + (size_t)r * 2048, slot + dst0);
        r = r0 + ro_1; r = r < 0 ? 0 : (r > IMG - 1 ? IMG - 1 : r);
        gload16(base1 + (size_t)r * 2048, slot + dst1);
        if (has3) {
            r = r0 + ro_2; r = r < 0 ? 0 : (r > IMG - 1 ? IMG - 1 : r);
            gload16(base2 + (size_t)r * 2048, slot + dst2);
        }
    };

    // Readback offsets (per-lane constants).
    const int rb0 = wave * 64 + quad * 32;             // window byte, piece 0
    const int ro0 = lm * RSTR + rb0;
    const int ro1 = ro0 + 16;
    auto read_g = [&](int k, float4 (&L)[4], bool rowsE) {
        const char* s = &raw[k & 1][0];
        L[0] = *(const float4*)(s + ro0);
        L[1] = *(const float4*)(s + ro1);
        L[2] = *(const float4*)(s + SLAB + ro0);
        L[3] = *(const float4*)(s + SLAB + ro1);
        lwait0();
        if (!colOK || rowsE) {                         // wave-uniform branch
            const int gr = rowbase + k * 16 - 8 + lm;
            const bool rbad = (unsigned)gr >= (unsigned)IMG;
            float4 zz; zz.x = zz.y = zz.z = zz.w = 0.f;
            if (rbad | cbA) { L[0] = zz; L[2] = zz; }
            if (rbad | cbB) { L[1] = zz; L[3] = zz; }
        }
    };

    f2 vsum = {0.f, 0.f};
    float4 L[4];

    // Pipeline (depth-1 cross-block-cooperative):
    //   per granule k: vwait(own n) -> bar1 (all waves' k-writes visible)
    //   -> read k + lwait0 -> bar2 (all done reading slot k&1) ->
    //   issue k+2 (rewrites slot k&1) -> h(k) -> v(k-1).
    issue_g(0); issue_g(1);

    // k = 0
    if (has3) vwait<3>(); else vwait<2>();
    blockbar();
    read_g(0, L, topE);
    blockbar();
    issue_g(2);
    h_rt(L, band, hw, lm, quad, 0);

    #pragma unroll 2
    for (int k = 1; k <= NG - 2; ++k) {                // k = 1..6
        if (has3) vwait<3>(); else vwait<2>();
        blockbar();
        read_g(k, L, false);
        blockbar();
        issue_g(k + 2);
        h_rt(L, band, hw, lm, quad, k & 1);
        v_t2(band, hw, lm, quad, k - 1, vsum);
    }

    // k = NG-1 = 7 (no more issues)
    if (has3) vwait<3>(); else vwait<2>();
    blockbar();
    read_g(NG - 1, L, false);
    h_rt(L, band, hw, lm, quad, (NG - 1) & 1);
    v_t2(band, hw, lm, quad, NG - 2, vsum);

    // k = NG = 8 (possible bottom edge)
    vwait<0>();
    blockbar();
    read_g(NG, L, botE);
    h_rt(L, band, hw, lm, quad, NG & 1);
    v_t2(band, hw, lm, quad, NG - 1, vsum);

    // ---- wave reduction -> per-BLOCK partial (raw ring is dead) ----
    float vs = vsum.x + vsum.y;
    #pragma unroll
    for (int off = 32; off > 0; off >>= 1)
        vs += __shfl_down(vs, off, 64);
    if (lane == 0) *(float*)&raw[0][wave * 4] = vs;
    __syncthreads();                                   // end of kernel: OK
    if (tid == 0) {
        float t = 0.f;
        #pragma unroll
        for (int w = 0; w < 16; ++w) t += *(const float*)&raw[0][w * 4];
        partial[(z * GYB + byb) * GXC + bxc] = t;
    }
}

__global__ __launch_bounds__(512) void finalize_kernel(
    const float* __restrict__ partial, float* __restrict__ out)
{
    __shared__ float red[8];
    float s = 0.f;
    if (threadIdx.x < NPART / 4) {                     // 96 float4s
        const float4 t = ((const float4*)partial)[threadIdx.x];
        s = (t.x + t.y) + (t.z + t.w);
    }
    #pragma unroll
    for (int off = 32; off > 0; off >>= 1)
        s += __shfl_down(s, off, 64);
    if ((threadIdx.x & 63) == 0) red[threadIdx.x >> 6] = s;
    __syncthreads();
    if (threadIdx.x == 0) {
        float t = 0.f;
        #pragma unroll
        for (int i = 0; i < 8; ++i) t += red[i];
        out[0] = 1.0f - t / (float)NPIX;
    }
}

extern "C" void kernel_launch(void* const* d_in, const int* in_sizes, int n_in,
                              void* d_out, int out_size, void* d_ws, size_t ws_size,
                              hipStream_t stream) {
    const float* img1 = (const float*)d_in[0];
    const float* img2 = (const float*)d_in[1];
    const float* win  = (const float*)d_in[2];
    float* partialb = (float*)d_ws;  // NPART floats = 1.5 KB; fully rewritten

    dim3 grid(GXC, GYB, 48);
    ssim_kernel<<<grid, dim3(1024), 0, stream>>>(img1, img2, win, partialb);
    finalize_kernel<<<1, dim3(512), 0, stream>>>(partialb, (float*)d_out);
}